// Round 3
// baseline (212.339 us; speedup 1.0000x reference)
//
#include <hip/hip_runtime.h>
#include <math.h>

// ---------------------------------------------------------------------------
// YOLOv5 head (R9): 2 kernels.
// R8 post-mortem: cross-round subtraction -> kc_score still ~28 us (largest
// controllable chunk): per-candidate GEMV = 128-deep serial chain of IC-
// latency WT loads (unroll 8 -> ~16 round trips) x ~2 serial candidates,
// plus a full kernel boundary for the tiny KD.
// R9:
//   KB: unchanged (dense obj GEMV + WT pack + per-block candidate regions);
//       also zeroes 8 per-image counters + the done word (boundary-ordered).
//   KC+KD fused (kc_nms): block-per-candidate GEMV with 8-way c-split
//       (half-wave = c-slice) x float4 rows (32 lanes x 4 rows = 128),
//       unroll 16 -> ~4 latency round trips per candidate. Then rocPRIM-style
//       last-block pattern: __syncthreads; t0 {__threadfence; atomicAdd done};
//       last block __threadfence (acquire) and runs greedy NMS for all 8
//       images (scores staged in LDS, boxes read from global; actual counts
//       are tiny).
// ---------------------------------------------------------------------------

#define IMG_F 640.0f

// ws layout (units: 4-byte words)
#define WT_F     0               // transposed weights [level][a][c][128]
#define N_WT     344064          //   row l innermost, pad l>=85 = 0
#define WT_L0    0               // 3*128*128
#define WT_L1    49152           // 3*256*128
#define WT_L2    147456          // 3*512*128
#define CNTB_F   344064          // 700 ints: per-KB-block candidate count
#define IMGCNT_F 344768          // 8 ints: per-image box count (KC atomics)
#define DONE_F   344776          // 1 int: blocks-done counter (last-block KD)
#define NSLOT    64              // candidate slots per KB block
#define CANDB_F  344780          // 700 x NSLOT x {code:int, obj:float}
#define IMGBUF_F (CANDB_F + 700 * NSLOT * 2)   // = 434380; 8 x CAP2 x 6 floats
#define CAP2     2048
// total = 532684 words ~= 2.1 MB of d_ws

#define LOGIT_T (-2.1972245773362196f)   // logit(0.1)

__constant__ float d_anch[3][3][2] = {
  {{6.1f,8.1f},{20.6f,12.6f},{11.2f,23.7f}},
  {{36.2f,26.8f},{25.9f,57.2f},{57.8f,47.9f}},
  {{122.1f,78.3f},{73.7f,143.8f},{236.1f,213.1f}},
};
__constant__ float d_stridec[3] = {8.f,16.f,32.f};

// ------------- KB: WT pack + dense obj GEMV + per-block candidates ---------
//   L0: blocks [0,400):   Q=32, S=8   (C=128, HW=6400)
//   L1: blocks [400,600): Q=16, S=16  (C=256, HW=1600)
//   L2: blocks [600,700): Q=8,  S=32  (C=512, HW=400)
__global__ __launch_bounds__(256) void kb_obj(
    const float* __restrict__ f0, const float* __restrict__ f1,
    const float* __restrict__ f2,
    const float* __restrict__ w0, const float* __restrict__ w1,
    const float* __restrict__ w2,
    const float* __restrict__ b0, const float* __restrict__ b1,
    const float* __restrict__ b2, float* __restrict__ ws) {
  __shared__ float red[3104];            // max S*(Q*12+1) over levels
  __shared__ int lcnt;
  int b = blockIdx.x, t = threadIdx.x;
  if (t == 0) lcnt = 0;
  if (b == 0 && t < 9) ((int*)ws)[IMGCNT_F + t] = 0;  // 8 img counters + done
  // WT pack: wT[level][a][c][128], row l innermost, pad l>=85 -> 0.
  for (int i = b * 256 + t; i < N_WT; i += 700 * 256) {
    int C, i2; const float* w;
    if (i < WT_L1)      { C = 128; i2 = i;         w = w0; }
    else if (i < WT_L2) { C = 256; i2 = i - WT_L1; w = w1; }
    else                { C = 512; i2 = i - WT_L2; w = w2; }
    int a = i2 / (C * 128);
    int r = i2 - a * (C * 128);
    int c = r >> 7, l = r & 127;
    ws[WT_F + i] = (l < 85) ? w[(size_t)(a * 85 + l) * C + c] : 0.f;
  }
  int level, Q, lq, S, bq0, C, HW;
  const float *f, *w, *bb;
  if (b < 400)      { level = 0; Q = 32; lq = 5; S = 8;  bq0 = b * 32;         C = 128; HW = 6400; f = f0; w = w0; bb = b0; }
  else if (b < 600) { level = 1; Q = 16; lq = 4; S = 16; bq0 = (b - 400) * 16; C = 256; HW = 1600; f = f1; w = w1; bb = b1; }
  else              { level = 2; Q = 8;  lq = 3; S = 32; bq0 = (b - 600) * 8;  C = 512; HW = 400;  f = f2; w = w2; bb = b2; }
  int q = t & (Q - 1), sl = t >> lq;
  int qpi = HW >> 2;
  int gq = bq0 + q;
  int n = gq / qpi;
  int sq = (gq - n * qpi) << 2;
  int kbase = sl * 16;                   // C/S == 16 for all levels
  const float* fp = f + ((size_t)(n * C + kbase)) * HW + sq;
  const float* wp = w + 4 * C + kbase;   // obj row for a=0; a=1:+85C; a=2:+170C
  float acc[3][4] = {{0.f,0.f,0.f,0.f},{0.f,0.f,0.f,0.f},{0.f,0.f,0.f,0.f}};
  #pragma unroll
  for (int c = 0; c < 16; ++c) {
    float4 v = *(const float4*)(fp + (size_t)c * HW);   // 16 B/lane coalesced
    float wa0 = wp[c];
    float wa1 = wp[85 * C + c];
    float wa2 = wp[170 * C + c];
    acc[0][0] = fmaf(v.x, wa0, acc[0][0]); acc[0][1] = fmaf(v.y, wa0, acc[0][1]);
    acc[0][2] = fmaf(v.z, wa0, acc[0][2]); acc[0][3] = fmaf(v.w, wa0, acc[0][3]);
    acc[1][0] = fmaf(v.x, wa1, acc[1][0]); acc[1][1] = fmaf(v.y, wa1, acc[1][1]);
    acc[1][2] = fmaf(v.z, wa1, acc[1][2]); acc[1][3] = fmaf(v.w, wa1, acc[1][3]);
    acc[2][0] = fmaf(v.x, wa2, acc[2][0]); acc[2][1] = fmaf(v.y, wa2, acc[2][1]);
    acc[2][2] = fmaf(v.z, wa2, acc[2][2]); acc[2][3] = fmaf(v.w, wa2, acc[2][3]);
  }
  // LDS: red[sl*(Q*12+1) + q*12 + a*4+p]; odd slice stride, conflict-free.
  int stride = Q * 12 + 1;
  int base = sl * stride + q * 12;
  #pragma unroll
  for (int a = 0; a < 3; ++a)
    #pragma unroll
    for (int p = 0; p < 4; ++p)
      red[base + a * 4 + p] = acc[a][p];
  __syncthreads();                       // also covers lcnt init
  for (int r = t; r < Q * 12; r += 256) {
    int qq = r / 12, ap = r - qq * 12;
    int a = ap >> 2, p = ap & 3;
    float sum = 0.f;
    for (int s2 = 0; s2 < S; ++s2) sum += red[s2 * stride + qq * 12 + ap];
    float logit = sum + bb[a * 85 + 4];
    if (logit > LOGIT_T) {               // sigmoid(x)>0.1 <=> x>logit(0.1)
      float obj = 1.f / (1.f + expf(-logit));
      int gq2 = bq0 + qq;
      int n2 = gq2 / qpi;
      int s = ((gq2 - n2 * qpi) << 2) + p;
      int idx = atomicAdd(&lcnt, 1);     // LDS atomic, no global contention
      if (idx < NSLOT) {
        int* cd = (int*)ws + CANDB_F + (b * NSLOT + idx) * 2;
        cd[0] = (n2 << 24) | (level << 20) | (a << 16) | s;
        ((float*)cd)[1] = obj;
      }
    }
  }
  __syncthreads();
  if (t == 0) ((int*)ws)[CNTB_F + b] = min(lcnt, NSLOT);  // sole writer
}

// -------- candidate GEMV: 8-way c-split x float4 rows, deep unroll ---------
// out[l] = sum_c f[n,c,s] * wT[a][c][l].  Half-wave (tid>>5) owns c-slice
// [slice*C/8,(slice+1)*C/8); lane5 = tid&31 covers rows 4*lane5..+3 via
// float4 (512 B coalesced per half-wave per c). 8 partials/row in LDS,
// reduce -> sigmoid -> box + class-threshold push.
template<int C, int HW, int Wd>
__device__ __forceinline__ void kc_block(
    int level, int n, int a, int s, float obj,
    const float* __restrict__ f, const float* __restrict__ wTl,
    const float* __restrict__ bb, float* __restrict__ ws,
    float* __restrict__ fc, float* __restrict__ partial,
    float* __restrict__ sig, int tid) {
  for (int i = tid; i < C; i += 256)               // stage f column
    fc[i] = f[((size_t)(n * C + i)) * HW + s];
  __syncthreads();
  int slice = tid >> 5, lane5 = tid & 31;
  const float* wA = wTl + (size_t)a * C * 128;
  constexpr int CS = C / 8;
  const float* wp = wA + (size_t)(slice * CS) * 128 + 4 * lane5;
  const float* fq = fc + slice * CS;
  float4 acc = {0.f, 0.f, 0.f, 0.f};
  #pragma unroll 16
  for (int c = 0; c < CS; ++c) {
    float fv = fq[c];                              // LDS broadcast
    float4 wv = *(const float4*)(wp + (size_t)c * 128);
    acc.x = fmaf(fv, wv.x, acc.x);
    acc.y = fmaf(fv, wv.y, acc.y);
    acc.z = fmaf(fv, wv.z, acc.z);
    acc.w = fmaf(fv, wv.w, acc.w);
  }
  *(float4*)(partial + slice * 128 + 4 * lane5) = acc;
  __syncthreads();
  if (tid < 85) {
    float sum = 0.f;
    #pragma unroll
    for (int k = 0; k < 8; ++k) sum += partial[k * 128 + tid];
    float logit = sum + bb[a * 85 + tid];
    sig[tid] = 1.f / (1.f + expf(-logit));
  }
  __syncthreads();
  float p0 = sig[0], p1 = sig[1], p2 = sig[2], p3 = sig[3];
  int gx = s % Wd, gy = s / Wd;
  float st = d_stridec[level];
  float cx = (2.f * p0 - 0.5f + (float)gx) * st;
  float cy = (2.f * p1 - 0.5f + (float)gy) * st;
  float bw = 4.f * p2 * p2 * d_anch[level][a][0];
  float bh = 4.f * p3 * p3 * d_anch[level][a][1];
  float x1 = fminf(fmaxf(cx - bw * 0.5f, 0.f), IMG_F);
  float y1 = fminf(fmaxf(cy - bh * 0.5f, 0.f), IMG_F);
  float x2 = fminf(fmaxf(cx + bw * 0.5f, 0.f), IMG_F);
  float y2 = fminf(fmaxf(cy + bh * 0.5f, 0.f), IMG_F);
  if (tid >= 5 && tid < 85) {                      // classes 0..79
    float sc = obj * sig[tid];
    if (sc > 0.1f) {
      int p = atomicAdd((int*)ws + IMGCNT_F + n, 1);
      if (p < CAP2) {
        float* dst = ws + IMGBUF_F + ((size_t)(n * CAP2 + p)) * 6;
        dst[0] = x1; dst[1] = y1; dst[2] = x2; dst[3] = y2;
        dst[4] = sc; dst[5] = (float)(tid - 5);
      }
    }
  }
  __syncthreads();                                 // LDS reuse across items
}

// -------- KC+KD fused: scoring blocks + last-block greedy NMS --------------
__global__ __launch_bounds__(256) void kc_nms(
    const float* __restrict__ f0, const float* __restrict__ f1,
    const float* __restrict__ f2,
    const float* __restrict__ b0, const float* __restrict__ b1,
    const float* __restrict__ b2, float* __restrict__ ws,
    float* __restrict__ out, const float* __restrict__ sfp) {
  __shared__ float smem[2576];     // scoring: fc 512 | partial 1024 | sig 85
  __shared__ int isLast;           // nms: bscv 2048 | rs 256 | ri 256 | bc 16
  int tid = threadIdx.x;
  int reg = blockIdx.x >> 3, ci0 = blockIdx.x & 7;  // grid = 700*8
  float* fc = smem;
  float* partial = smem + 512;
  float* sig = smem + 1536;
  int cnt = min(((int*)ws)[CNTB_F + reg], NSLOT);
  for (int ci = ci0; ci < cnt; ci += 8) {           // uniform per block
    int* cd = (int*)ws + CANDB_F + (reg * NSLOT + ci) * 2;
    int code = cd[0]; float obj = ((float*)cd)[1];
    int n = code >> 24, level = (code >> 20) & 15, a = (code >> 16) & 3, s = code & 0xFFFF;
    if (level == 0)
      kc_block<128, 6400, 80>(0, n, a, s, obj, f0, ws + WT_F + WT_L0, b0, ws, fc, partial, sig, tid);
    else if (level == 1)
      kc_block<256, 1600, 40>(1, n, a, s, obj, f1, ws + WT_F + WT_L1, b1, ws, fc, partial, sig, tid);
    else
      kc_block<512, 400, 20>(2, n, a, s, obj, f2, ws + WT_F + WT_L2, b2, ws, fc, partial, sig, tid);
  }
  // ---- done-signal (rocPRIM last-block pattern) ----
  __syncthreads();                 // all pushes issued; vmcnt drained at barrier
  if (tid == 0) {
    __threadfence();               // release: flush L2 to device-visible
    int old = atomicAdd((int*)ws + DONE_F, 1);
    isLast = (old == (int)gridDim.x - 1);
  }
  __syncthreads();
  if (!isLast) return;
  __threadfence();                 // acquire: invalidate stale lines
  // ---- greedy NMS, all 8 images, sequential (actual counts are tiny) ----
  float* bscv = smem;              // 2048: score, -1 = suppressed
  float* rs   = smem + 2048;       // 256
  int*   ri   = (int*)(smem + 2304);
  float* bc   = smem + 2560;       // winner broadcast
  for (int n = 0; n < 8; ++n) {
    float sf = sfp[n];
    int bcnt = min(((int*)ws)[IMGCNT_F + n], CAP2);
    const float* ibuf = ws + IMGBUF_F + (size_t)n * CAP2 * 6;
    for (int i = tid; i < bcnt; i += 256) bscv[i] = ibuf[(size_t)i * 6 + 4];
    __syncthreads();
    for (int it = 0; it < 100; ++it) {
      float best = -1.f; int bi = -1;
      for (int i = tid; i < bcnt; i += 256)
        if (bscv[i] > best) { best = bscv[i]; bi = i; }
      rs[tid] = best; ri[tid] = bi;
      __syncthreads();
      for (int off = 128; off > 0; off >>= 1) {
        if (tid < off && rs[tid + off] > rs[tid]) { rs[tid] = rs[tid + off]; ri[tid] = ri[tid + off]; }
        __syncthreads();
      }
      int wi = ri[0]; float wsc = rs[0];
      if (wi < 0 || wsc <= 0.f) {   // none left: zero-fill remaining rows
        for (int r2 = it * 6 + tid; r2 < 600; r2 += 256)
          out[(size_t)n * 600 + r2] = 0.f;
        break;                      // uniform (wi/wsc from LDS broadcast)
      }
      if (tid == 0) {
        const float* src = ibuf + (size_t)wi * 6;
        float x1 = src[0], y1 = src[1], x2 = src[2], y2 = src[3], lb = src[5];
        float* o = out + (size_t)(n * 100 + it) * 6;
        o[0] = x1 / sf; o[1] = y1 / sf; o[2] = x2 / sf; o[3] = y2 / sf;
        o[4] = wsc;     o[5] = lb;
        float ofw = lb * IMG_F;     // class-offset boxes for IoU
        bc[0] = x1 + ofw; bc[1] = y1 + ofw; bc[2] = x2 + ofw; bc[3] = y2 + ofw;
        bc[4] = (x2 - x1) * (y2 - y1);
        bscv[wi] = -1.f;
      }
      __syncthreads();
      float wx1 = bc[0], wy1 = bc[1], wx2 = bc[2], wy2 = bc[3], wa = bc[4];
      for (int i = tid; i < bcnt; i += 256) {
        if (bscv[i] > 0.f) {
          const float* s2 = ibuf + (size_t)i * 6;
          float o2 = s2[5] * IMG_F;
          float x1 = s2[0] + o2, y1 = s2[1] + o2, x2 = s2[2] + o2, y2 = s2[3] + o2;
          float iw = fmaxf(fminf(wx2, x2) - fmaxf(wx1, x1), 0.f);
          float ih = fmaxf(fminf(wy2, y2) - fmaxf(wy1, y1), 0.f);
          float inter = iw * ih;
          float area = (x2 - x1) * (y2 - y1);
          float iou = inter / (wa + area - inter + 1e-7f);
          if (iou > 0.6f) bscv[i] = -1.f;
        }
      }
      __syncthreads();
    }
    __syncthreads();               // before next image restages bscv
  }
}

// ---------------------------------------------------------------------------
extern "C" void kernel_launch(void* const* d_in, const int* in_sizes, int n_in,
                              void* d_out, int out_size, void* d_ws, size_t ws_size,
                              hipStream_t stream) {
  // setup_inputs() dict order: f0,w0,b0, f1,w1,b1, f2,w2,b2, scale_factors
  const float* f0 = (const float*)d_in[0];
  const float* w0 = (const float*)d_in[1];
  const float* b0 = (const float*)d_in[2];
  const float* f1 = (const float*)d_in[3];
  const float* w1 = (const float*)d_in[4];
  const float* b1 = (const float*)d_in[5];
  const float* f2 = (const float*)d_in[6];
  const float* w2 = (const float*)d_in[7];
  const float* b2 = (const float*)d_in[8];
  const float* sf = (const float*)d_in[9];
  float* out = (float*)d_out;
  float* ws  = (float*)d_ws;    // needs ~2.1 MB

  kb_obj <<<700,     256, 0, stream>>>(f0, f1, f2, w0, w1, w2, b0, b1, b2, ws);
  kc_nms <<<700 * 8, 256, 0, stream>>>(f0, f1, f2, b0, b1, b2, ws, out, sf);
}

// Round 4
// 120.597 us; speedup vs baseline: 1.7607x; 1.7607x over previous
//
#include <hip/hip_runtime.h>
#include <math.h>

// ---------------------------------------------------------------------------
// YOLOv5 head (R10): 3 kernels — R8 structure + R9's deeper GEMV, NO fences.
// R9 post-mortem: last-block fusion cost +86 us. Device-scope __threadfence
// + 5600 same-address device atomics = per-XCD L2 writeback/invalidate storm
// (hbm flat ~102 GB/s, VALU 0.6% -- same signature as R4/R5 grid.sync).
// On multi-XCD CDNA a kernel boundary is CHEAPER than any in-kernel
// device-scope ordering. NMS itself was trivial (counts ~0).
// R10:
//   KB: dense obj GEMV + WT pack + per-block candidate regions (R8, proven)
//   KC: block-per-candidate scoring, 8-way c-split x float4 rows, unroll 16
//       (~4 latency round trips vs R8's ~16)  [R9's GEMV, kept]
//   KD: per-image greedy NMS, 8 blocks (R8, proven)
// ---------------------------------------------------------------------------

#define IMG_F 640.0f

// ws layout (units: 4-byte words)
#define WT_F     0               // transposed weights [level][a][c][128]
#define N_WT     344064          //   row l innermost, pad l>=85 = 0
#define WT_L0    0               // 3*128*128
#define WT_L1    49152           // 3*256*128
#define WT_L2    147456          // 3*512*128
#define CNTB_F   344064          // 700 ints: per-KB-block candidate count
#define IMGCNT_F 344768          // 8 ints: per-image box count (KC atomics)
#define NSLOT    64              // candidate slots per KB block
#define CANDB_F  344776          // 700 x NSLOT x {code:int, obj:float}
#define IMGBUF_F (CANDB_F + 700 * NSLOT * 2)   // = 434376; 8 x CAP2 x 6 floats
#define CAP2     2048
// total = 532680 words ~= 2.1 MB of d_ws

#define LOGIT_T (-2.1972245773362196f)   // logit(0.1)

__constant__ float d_anch[3][3][2] = {
  {{6.1f,8.1f},{20.6f,12.6f},{11.2f,23.7f}},
  {{36.2f,26.8f},{25.9f,57.2f},{57.8f,47.9f}},
  {{122.1f,78.3f},{73.7f,143.8f},{236.1f,213.1f}},
};
__constant__ float d_stridec[3] = {8.f,16.f,32.f};

// ------------- KB: WT pack + dense obj GEMV + per-block candidates ---------
//   L0: blocks [0,400):   Q=32, S=8   (C=128, HW=6400)
//   L1: blocks [400,600): Q=16, S=16  (C=256, HW=1600)
//   L2: blocks [600,700): Q=8,  S=32  (C=512, HW=400)
__global__ __launch_bounds__(256) void kb_obj(
    const float* __restrict__ f0, const float* __restrict__ f1,
    const float* __restrict__ f2,
    const float* __restrict__ w0, const float* __restrict__ w1,
    const float* __restrict__ w2,
    const float* __restrict__ b0, const float* __restrict__ b1,
    const float* __restrict__ b2, float* __restrict__ ws) {
  __shared__ float red[3104];            // max S*(Q*12+1) over levels
  __shared__ int lcnt;
  int b = blockIdx.x, t = threadIdx.x;
  if (t == 0) lcnt = 0;
  if (b == 0 && t < 8) ((int*)ws)[IMGCNT_F + t] = 0;   // visible before KC
  // WT pack: wT[level][a][c][128], row l innermost, pad l>=85 -> 0.
  for (int i = b * 256 + t; i < N_WT; i += 700 * 256) {
    int C, i2; const float* w;
    if (i < WT_L1)      { C = 128; i2 = i;         w = w0; }
    else if (i < WT_L2) { C = 256; i2 = i - WT_L1; w = w1; }
    else                { C = 512; i2 = i - WT_L2; w = w2; }
    int a = i2 / (C * 128);
    int r = i2 - a * (C * 128);
    int c = r >> 7, l = r & 127;
    ws[WT_F + i] = (l < 85) ? w[(size_t)(a * 85 + l) * C + c] : 0.f;
  }
  int level, Q, lq, S, bq0, C, HW;
  const float *f, *w, *bb;
  if (b < 400)      { level = 0; Q = 32; lq = 5; S = 8;  bq0 = b * 32;         C = 128; HW = 6400; f = f0; w = w0; bb = b0; }
  else if (b < 600) { level = 1; Q = 16; lq = 4; S = 16; bq0 = (b - 400) * 16; C = 256; HW = 1600; f = f1; w = w1; bb = b1; }
  else              { level = 2; Q = 8;  lq = 3; S = 32; bq0 = (b - 600) * 8;  C = 512; HW = 400;  f = f2; w = w2; bb = b2; }
  int q = t & (Q - 1), sl = t >> lq;
  int qpi = HW >> 2;
  int gq = bq0 + q;
  int n = gq / qpi;
  int sq = (gq - n * qpi) << 2;
  int kbase = sl * 16;                   // C/S == 16 for all levels
  const float* fp = f + ((size_t)(n * C + kbase)) * HW + sq;
  const float* wp = w + 4 * C + kbase;   // obj row for a=0; a=1:+85C; a=2:+170C
  float acc[3][4] = {{0.f,0.f,0.f,0.f},{0.f,0.f,0.f,0.f},{0.f,0.f,0.f,0.f}};
  #pragma unroll
  for (int c = 0; c < 16; ++c) {
    float4 v = *(const float4*)(fp + (size_t)c * HW);   // 16 B/lane coalesced
    float wa0 = wp[c];
    float wa1 = wp[85 * C + c];
    float wa2 = wp[170 * C + c];
    acc[0][0] = fmaf(v.x, wa0, acc[0][0]); acc[0][1] = fmaf(v.y, wa0, acc[0][1]);
    acc[0][2] = fmaf(v.z, wa0, acc[0][2]); acc[0][3] = fmaf(v.w, wa0, acc[0][3]);
    acc[1][0] = fmaf(v.x, wa1, acc[1][0]); acc[1][1] = fmaf(v.y, wa1, acc[1][1]);
    acc[1][2] = fmaf(v.z, wa1, acc[1][2]); acc[1][3] = fmaf(v.w, wa1, acc[1][3]);
    acc[2][0] = fmaf(v.x, wa2, acc[2][0]); acc[2][1] = fmaf(v.y, wa2, acc[2][1]);
    acc[2][2] = fmaf(v.z, wa2, acc[2][2]); acc[2][3] = fmaf(v.w, wa2, acc[2][3]);
  }
  // LDS: red[sl*(Q*12+1) + q*12 + a*4+p]; odd slice stride, conflict-free.
  int stride = Q * 12 + 1;
  int base = sl * stride + q * 12;
  #pragma unroll
  for (int a = 0; a < 3; ++a)
    #pragma unroll
    for (int p = 0; p < 4; ++p)
      red[base + a * 4 + p] = acc[a][p];
  __syncthreads();                       // also covers lcnt init
  for (int r = t; r < Q * 12; r += 256) {
    int qq = r / 12, ap = r - qq * 12;
    int a = ap >> 2, p = ap & 3;
    float sum = 0.f;
    for (int s2 = 0; s2 < S; ++s2) sum += red[s2 * stride + qq * 12 + ap];
    float logit = sum + bb[a * 85 + 4];
    if (logit > LOGIT_T) {               // sigmoid(x)>0.1 <=> x>logit(0.1)
      float obj = 1.f / (1.f + expf(-logit));
      int gq2 = bq0 + qq;
      int n2 = gq2 / qpi;
      int s = ((gq2 - n2 * qpi) << 2) + p;
      int idx = atomicAdd(&lcnt, 1);     // LDS atomic, no global contention
      if (idx < NSLOT) {
        int* cd = (int*)ws + CANDB_F + (b * NSLOT + idx) * 2;
        cd[0] = (n2 << 24) | (level << 20) | (a << 16) | s;
        ((float*)cd)[1] = obj;
      }
    }
  }
  __syncthreads();
  if (t == 0) ((int*)ws)[CNTB_F + b] = min(lcnt, NSLOT);  // sole writer
}

// -------- candidate GEMV: 8-way c-split x float4 rows, deep unroll ---------
// out[l] = sum_c f[n,c,s] * wT[a][c][l].  Half-wave (tid>>5) owns c-slice
// [slice*C/8,(slice+1)*C/8); lane5 = tid&31 covers rows 4*lane5..+3 via
// float4 (512 B coalesced per half-wave per c). 8 partials/row in LDS,
// reduce -> sigmoid -> box + class-threshold push.
template<int C, int HW, int Wd>
__device__ __forceinline__ void kc_block(
    int level, int n, int a, int s, float obj,
    const float* __restrict__ f, const float* __restrict__ wTl,
    const float* __restrict__ bb, float* __restrict__ ws,
    float* __restrict__ fc, float* __restrict__ partial,
    float* __restrict__ sig, int tid) {
  for (int i = tid; i < C; i += 256)               // stage f column
    fc[i] = f[((size_t)(n * C + i)) * HW + s];
  __syncthreads();
  int slice = tid >> 5, lane5 = tid & 31;
  const float* wA = wTl + (size_t)a * C * 128;
  constexpr int CS = C / 8;
  const float* wp = wA + (size_t)(slice * CS) * 128 + 4 * lane5;
  const float* fq = fc + slice * CS;
  float4 acc = {0.f, 0.f, 0.f, 0.f};
  #pragma unroll 16
  for (int c = 0; c < CS; ++c) {
    float fv = fq[c];                              // LDS broadcast
    float4 wv = *(const float4*)(wp + (size_t)c * 128);
    acc.x = fmaf(fv, wv.x, acc.x);
    acc.y = fmaf(fv, wv.y, acc.y);
    acc.z = fmaf(fv, wv.z, acc.z);
    acc.w = fmaf(fv, wv.w, acc.w);
  }
  *(float4*)(partial + slice * 128 + 4 * lane5) = acc;
  __syncthreads();
  if (tid < 85) {
    float sum = 0.f;
    #pragma unroll
    for (int k = 0; k < 8; ++k) sum += partial[k * 128 + tid];
    float logit = sum + bb[a * 85 + tid];
    sig[tid] = 1.f / (1.f + expf(-logit));
  }
  __syncthreads();
  float p0 = sig[0], p1 = sig[1], p2 = sig[2], p3 = sig[3];
  int gx = s % Wd, gy = s / Wd;
  float st = d_stridec[level];
  float cx = (2.f * p0 - 0.5f + (float)gx) * st;
  float cy = (2.f * p1 - 0.5f + (float)gy) * st;
  float bw = 4.f * p2 * p2 * d_anch[level][a][0];
  float bh = 4.f * p3 * p3 * d_anch[level][a][1];
  float x1 = fminf(fmaxf(cx - bw * 0.5f, 0.f), IMG_F);
  float y1 = fminf(fmaxf(cy - bh * 0.5f, 0.f), IMG_F);
  float x2 = fminf(fmaxf(cx + bw * 0.5f, 0.f), IMG_F);
  float y2 = fminf(fmaxf(cy + bh * 0.5f, 0.f), IMG_F);
  if (tid >= 5 && tid < 85) {                      // classes 0..79
    float sc = obj * sig[tid];
    if (sc > 0.1f) {
      int p = atomicAdd((int*)ws + IMGCNT_F + n, 1);
      if (p < CAP2) {
        float* dst = ws + IMGBUF_F + ((size_t)(n * CAP2 + p)) * 6;
        dst[0] = x1; dst[1] = y1; dst[2] = x2; dst[3] = y2;
        dst[4] = sc; dst[5] = (float)(tid - 5);
      }
    }
  }
  __syncthreads();                                 // LDS reuse across items
}

__global__ __launch_bounds__(256) void kc_score(
    const float* __restrict__ f0, const float* __restrict__ f1,
    const float* __restrict__ f2,
    const float* __restrict__ b0, const float* __restrict__ b1,
    const float* __restrict__ b2, float* __restrict__ ws) {
  __shared__ float fc[512];
  __shared__ float partial[1024];
  __shared__ float sig[85];
  int tid = threadIdx.x;
  int reg = blockIdx.x >> 3, ci0 = blockIdx.x & 7;  // grid = 700*8
  int cnt = min(((int*)ws)[CNTB_F + reg], NSLOT);
  for (int ci = ci0; ci < cnt; ci += 8) {           // uniform per block
    int* cd = (int*)ws + CANDB_F + (reg * NSLOT + ci) * 2;
    int code = cd[0]; float obj = ((float*)cd)[1];
    int n = code >> 24, level = (code >> 20) & 15, a = (code >> 16) & 3, s = code & 0xFFFF;
    if (level == 0)
      kc_block<128, 6400, 80>(0, n, a, s, obj, f0, ws + WT_F + WT_L0, b0, ws, fc, partial, sig, tid);
    else if (level == 1)
      kc_block<256, 1600, 40>(1, n, a, s, obj, f1, ws + WT_F + WT_L1, b1, ws, fc, partial, sig, tid);
    else
      kc_block<512, 400, 20>(2, n, a, s, obj, f2, ws + WT_F + WT_L2, b2, ws, fc, partial, sig, tid);
  }
}

// ------------------------------------------ KD: per-image greedy NMS -------
// Writes its ENTIRE 600-float output slice (zero rows on early exit), so
// d_out needs no pre-zeroing kernel.
__global__ __launch_bounds__(256) void kd_nms(
    const float* __restrict__ ws, float* __restrict__ out,
    const float* __restrict__ sfp) {
  __shared__ float bx1[CAP2], by1[CAP2], bx2[CAP2], by2[CAP2], bsc[CAP2], blb[CAP2];
  __shared__ int bval[CAP2];
  __shared__ float rs[256];
  __shared__ int ri[256];
  int n = blockIdx.x, tid = threadIdx.x;
  int cnt = min(((const int*)ws)[IMGCNT_F + n], CAP2);
  for (int i = tid; i < cnt; i += 256) {
    const float* src = ws + IMGBUF_F + ((size_t)(n * CAP2 + i)) * 6;
    bx1[i] = src[0]; by1[i] = src[1]; bx2[i] = src[2]; by2[i] = src[3];
    bsc[i] = src[4]; blb[i] = src[5]; bval[i] = 1;
  }
  __syncthreads();
  float sf = sfp[n];
  for (int it = 0; it < 100; ++it) {
    float best = -1.f; int bi = -1;
    for (int i = tid; i < cnt; i += 256)
      if (bval[i] && bsc[i] > best) { best = bsc[i]; bi = i; }
    rs[tid] = best; ri[tid] = bi;
    __syncthreads();
    for (int off = 128; off > 0; off >>= 1) {
      if (tid < off && rs[tid + off] > rs[tid]) { rs[tid] = rs[tid + off]; ri[tid] = ri[tid + off]; }
      __syncthreads();
    }
    int wi = ri[0]; float wsc = rs[0];
    if (wi < 0) {                         // no valid left: zero-fill remaining
      for (int r2 = it * 6 + tid; r2 < 600; r2 += 256)
        out[(size_t)n * 600 + r2] = 0.f;
      break;
    }
    if (tid == 0) {
      float* o = out + (size_t)(n * 100 + it) * 6;
      o[0] = bx1[wi] / sf; o[1] = by1[wi] / sf;
      o[2] = bx2[wi] / sf; o[3] = by2[wi] / sf;
      o[4] = wsc;          o[5] = blb[wi];
    }
    // suppress IoU > 0.6 on class-offset boxes (offset adds to all 4 coords)
    float ofw = blb[wi] * IMG_F;
    float wx1 = bx1[wi] + ofw, wy1 = by1[wi] + ofw;
    float wx2 = bx2[wi] + ofw, wy2 = by2[wi] + ofw;
    float wa = (wx2 - wx1) * (wy2 - wy1);
    for (int i = tid; i < cnt; i += 256) {
      if (bval[i]) {
        float o2 = blb[i] * IMG_F;
        float x1 = bx1[i] + o2, y1 = by1[i] + o2, x2 = bx2[i] + o2, y2 = by2[i] + o2;
        float iw = fmaxf(fminf(wx2, x2) - fmaxf(wx1, x1), 0.f);
        float ih = fmaxf(fminf(wy2, y2) - fmaxf(wy1, y1), 0.f);
        float inter = iw * ih;
        float area = (x2 - x1) * (y2 - y1);
        float iou = inter / (wa + area - inter + 1e-7f);
        if (iou > 0.6f) bval[i] = 0;
      }
    }
    if (tid == 0) bval[wi] = 0;
    __syncthreads();
  }
}

// ---------------------------------------------------------------------------
extern "C" void kernel_launch(void* const* d_in, const int* in_sizes, int n_in,
                              void* d_out, int out_size, void* d_ws, size_t ws_size,
                              hipStream_t stream) {
  // setup_inputs() dict order: f0,w0,b0, f1,w1,b1, f2,w2,b2, scale_factors
  const float* f0 = (const float*)d_in[0];
  const float* w0 = (const float*)d_in[1];
  const float* b0 = (const float*)d_in[2];
  const float* f1 = (const float*)d_in[3];
  const float* w1 = (const float*)d_in[4];
  const float* b1 = (const float*)d_in[5];
  const float* f2 = (const float*)d_in[6];
  const float* w2 = (const float*)d_in[7];
  const float* b2 = (const float*)d_in[8];
  const float* sf = (const float*)d_in[9];
  float* out = (float*)d_out;
  float* ws  = (float*)d_ws;    // needs ~2.1 MB

  kb_obj  <<<700,     256, 0, stream>>>(f0, f1, f2, w0, w1, w2, b0, b1, b2, ws);
  kc_score<<<700 * 8, 256, 0, stream>>>(f0, f1, f2, b0, b1, b2, ws);
  kd_nms  <<<8,       256, 0, stream>>>(ws, out, sf);
}

// Round 5
// 119.546 us; speedup vs baseline: 1.7762x; 1.0088x over previous
//
#include <hip/hip_runtime.h>
#include <math.h>

// ---------------------------------------------------------------------------
// YOLOv5 head (R11): R10 structure; KC staging eliminated.
// R10 post-mortem: 120.6 us total = ~85 us fixed harness (256MiB ws poison
// fill @80% peak + small memsets; established by R9 subtraction) + kb ~10
// + kc ~8-15 + kd ~3 + gaps ~5. kc's cost is per-candidate LATENCY round
// trips (stage-f 1 trip + barrier + GEMV 4 trips), not FLOPs.
// R11 KC: direct-load GEMV. The f value needed at each c is lane-uniform
// within a half-wave c-slice -> direct global load = 2-address gather per
// wave instr, L1-broadcast. No fc LDS, no staging barrier; unroll 32 ->
// ~2 latency batches per candidate (~1 us). KB/KD unchanged (proven).
// Decision rule: if delta is within noise (+-3 us), remaining time is
// harness-dominated and the pipeline is at its latency floor.
// ---------------------------------------------------------------------------

#define IMG_F 640.0f

// ws layout (units: 4-byte words)
#define WT_F     0               // transposed weights [level][a][c][128]
#define N_WT     344064          //   row l innermost, pad l>=85 = 0
#define WT_L0    0               // 3*128*128
#define WT_L1    49152           // 3*256*128
#define WT_L2    147456          // 3*512*128
#define CNTB_F   344064          // 700 ints: per-KB-block candidate count
#define IMGCNT_F 344768          // 8 ints: per-image box count (KC atomics)
#define NSLOT    64              // candidate slots per KB block
#define CANDB_F  344776          // 700 x NSLOT x {code:int, obj:float}
#define IMGBUF_F (CANDB_F + 700 * NSLOT * 2)   // = 434376; 8 x CAP2 x 6 floats
#define CAP2     2048
// total = 532680 words ~= 2.1 MB of d_ws

#define LOGIT_T (-2.1972245773362196f)   // logit(0.1)

__constant__ float d_anch[3][3][2] = {
  {{6.1f,8.1f},{20.6f,12.6f},{11.2f,23.7f}},
  {{36.2f,26.8f},{25.9f,57.2f},{57.8f,47.9f}},
  {{122.1f,78.3f},{73.7f,143.8f},{236.1f,213.1f}},
};
__constant__ float d_stridec[3] = {8.f,16.f,32.f};

// ------------- KB: WT pack + dense obj GEMV + per-block candidates ---------
//   L0: blocks [0,400):   Q=32, S=8   (C=128, HW=6400)
//   L1: blocks [400,600): Q=16, S=16  (C=256, HW=1600)
//   L2: blocks [600,700): Q=8,  S=32  (C=512, HW=400)
__global__ __launch_bounds__(256) void kb_obj(
    const float* __restrict__ f0, const float* __restrict__ f1,
    const float* __restrict__ f2,
    const float* __restrict__ w0, const float* __restrict__ w1,
    const float* __restrict__ w2,
    const float* __restrict__ b0, const float* __restrict__ b1,
    const float* __restrict__ b2, float* __restrict__ ws) {
  __shared__ float red[3104];            // max S*(Q*12+1) over levels
  __shared__ int lcnt;
  int b = blockIdx.x, t = threadIdx.x;
  if (t == 0) lcnt = 0;
  if (b == 0 && t < 8) ((int*)ws)[IMGCNT_F + t] = 0;   // visible before KC
  // WT pack: wT[level][a][c][128], row l innermost, pad l>=85 -> 0.
  for (int i = b * 256 + t; i < N_WT; i += 700 * 256) {
    int C, i2; const float* w;
    if (i < WT_L1)      { C = 128; i2 = i;         w = w0; }
    else if (i < WT_L2) { C = 256; i2 = i - WT_L1; w = w1; }
    else                { C = 512; i2 = i - WT_L2; w = w2; }
    int a = i2 / (C * 128);
    int r = i2 - a * (C * 128);
    int c = r >> 7, l = r & 127;
    ws[WT_F + i] = (l < 85) ? w[(size_t)(a * 85 + l) * C + c] : 0.f;
  }
  int level, Q, lq, S, bq0, C, HW;
  const float *f, *w, *bb;
  if (b < 400)      { level = 0; Q = 32; lq = 5; S = 8;  bq0 = b * 32;         C = 128; HW = 6400; f = f0; w = w0; bb = b0; }
  else if (b < 600) { level = 1; Q = 16; lq = 4; S = 16; bq0 = (b - 400) * 16; C = 256; HW = 1600; f = f1; w = w1; bb = b1; }
  else              { level = 2; Q = 8;  lq = 3; S = 32; bq0 = (b - 600) * 8;  C = 512; HW = 400;  f = f2; w = w2; bb = b2; }
  int q = t & (Q - 1), sl = t >> lq;
  int qpi = HW >> 2;
  int gq = bq0 + q;
  int n = gq / qpi;
  int sq = (gq - n * qpi) << 2;
  int kbase = sl * 16;                   // C/S == 16 for all levels
  const float* fp = f + ((size_t)(n * C + kbase)) * HW + sq;
  const float* wp = w + 4 * C + kbase;   // obj row for a=0; a=1:+85C; a=2:+170C
  float acc[3][4] = {{0.f,0.f,0.f,0.f},{0.f,0.f,0.f,0.f},{0.f,0.f,0.f,0.f}};
  #pragma unroll
  for (int c = 0; c < 16; ++c) {
    float4 v = *(const float4*)(fp + (size_t)c * HW);   // 16 B/lane coalesced
    float wa0 = wp[c];
    float wa1 = wp[85 * C + c];
    float wa2 = wp[170 * C + c];
    acc[0][0] = fmaf(v.x, wa0, acc[0][0]); acc[0][1] = fmaf(v.y, wa0, acc[0][1]);
    acc[0][2] = fmaf(v.z, wa0, acc[0][2]); acc[0][3] = fmaf(v.w, wa0, acc[0][3]);
    acc[1][0] = fmaf(v.x, wa1, acc[1][0]); acc[1][1] = fmaf(v.y, wa1, acc[1][1]);
    acc[1][2] = fmaf(v.z, wa1, acc[1][2]); acc[1][3] = fmaf(v.w, wa1, acc[1][3]);
    acc[2][0] = fmaf(v.x, wa2, acc[2][0]); acc[2][1] = fmaf(v.y, wa2, acc[2][1]);
    acc[2][2] = fmaf(v.z, wa2, acc[2][2]); acc[2][3] = fmaf(v.w, wa2, acc[2][3]);
  }
  // LDS: red[sl*(Q*12+1) + q*12 + a*4+p]; odd slice stride, conflict-free.
  int stride = Q * 12 + 1;
  int base = sl * stride + q * 12;
  #pragma unroll
  for (int a = 0; a < 3; ++a)
    #pragma unroll
    for (int p = 0; p < 4; ++p)
      red[base + a * 4 + p] = acc[a][p];
  __syncthreads();                       // also covers lcnt init
  for (int r = t; r < Q * 12; r += 256) {
    int qq = r / 12, ap = r - qq * 12;
    int a = ap >> 2, p = ap & 3;
    float sum = 0.f;
    for (int s2 = 0; s2 < S; ++s2) sum += red[s2 * stride + qq * 12 + ap];
    float logit = sum + bb[a * 85 + 4];
    if (logit > LOGIT_T) {               // sigmoid(x)>0.1 <=> x>logit(0.1)
      float obj = 1.f / (1.f + expf(-logit));
      int gq2 = bq0 + qq;
      int n2 = gq2 / qpi;
      int s = ((gq2 - n2 * qpi) << 2) + p;
      int idx = atomicAdd(&lcnt, 1);     // LDS atomic, no global contention
      if (idx < NSLOT) {
        int* cd = (int*)ws + CANDB_F + (b * NSLOT + idx) * 2;
        cd[0] = (n2 << 24) | (level << 20) | (a << 16) | s;
        ((float*)cd)[1] = obj;
      }
    }
  }
  __syncthreads();
  if (t == 0) ((int*)ws)[CNTB_F + b] = min(lcnt, NSLOT);  // sole writer
}

// -------- candidate GEMV: direct f loads (lane-uniform per half-wave) ------
// out[l] = sum_c f[n,c,s] * wT[a][c][l].  Half-wave (tid>>5) owns c-slice
// [slice*C/8,(slice+1)*C/8); lane5 = tid&31 covers rows 4*lane5..+3 via
// float4 (512 B coalesced per half-wave per c). f value per c is uniform
// within the half-wave -> direct global load = 2-address gather per wave
// instr (L1 broadcast); no LDS staging, no barrier. unroll 32 -> ~2
// latency batches per candidate. 8 partials/row in LDS, reduce -> sigmoid
// -> box + class-threshold push.
template<int C, int HW, int Wd>
__device__ __forceinline__ void kc_block(
    int level, int n, int a, int s, float obj,
    const float* __restrict__ f, const float* __restrict__ wTl,
    const float* __restrict__ bb, float* __restrict__ ws,
    float* __restrict__ partial, float* __restrict__ sig, int tid) {
  int slice = tid >> 5, lane5 = tid & 31;
  constexpr int CS = C / 8;
  const float* wp = wTl + (size_t)a * C * 128 + (size_t)(slice * CS) * 128 + 4 * lane5;
  const float* fp = f + ((size_t)(n * C + slice * CS)) * HW + s;
  float4 acc = {0.f, 0.f, 0.f, 0.f};
  #pragma unroll 32
  for (int c = 0; c < CS; ++c) {
    float fv = fp[(size_t)c * HW];                 // lane-uniform per half-wave
    float4 wv = *(const float4*)(wp + (size_t)c * 128);
    acc.x = fmaf(fv, wv.x, acc.x);
    acc.y = fmaf(fv, wv.y, acc.y);
    acc.z = fmaf(fv, wv.z, acc.z);
    acc.w = fmaf(fv, wv.w, acc.w);
  }
  *(float4*)(partial + slice * 128 + 4 * lane5) = acc;
  __syncthreads();
  if (tid < 85) {
    float sum = 0.f;
    #pragma unroll
    for (int k = 0; k < 8; ++k) sum += partial[k * 128 + tid];
    float logit = sum + bb[a * 85 + tid];
    sig[tid] = 1.f / (1.f + expf(-logit));
  }
  __syncthreads();
  float p0 = sig[0], p1 = sig[1], p2 = sig[2], p3 = sig[3];
  int gx = s % Wd, gy = s / Wd;
  float st = d_stridec[level];
  float cx = (2.f * p0 - 0.5f + (float)gx) * st;
  float cy = (2.f * p1 - 0.5f + (float)gy) * st;
  float bw = 4.f * p2 * p2 * d_anch[level][a][0];
  float bh = 4.f * p3 * p3 * d_anch[level][a][1];
  float x1 = fminf(fmaxf(cx - bw * 0.5f, 0.f), IMG_F);
  float y1 = fminf(fmaxf(cy - bh * 0.5f, 0.f), IMG_F);
  float x2 = fminf(fmaxf(cx + bw * 0.5f, 0.f), IMG_F);
  float y2 = fminf(fmaxf(cy + bh * 0.5f, 0.f), IMG_F);
  if (tid >= 5 && tid < 85) {                      // classes 0..79
    float sc = obj * sig[tid];
    if (sc > 0.1f) {
      int p = atomicAdd((int*)ws + IMGCNT_F + n, 1);
      if (p < CAP2) {
        float* dst = ws + IMGBUF_F + ((size_t)(n * CAP2 + p)) * 6;
        dst[0] = x1; dst[1] = y1; dst[2] = x2; dst[3] = y2;
        dst[4] = sc; dst[5] = (float)(tid - 5);
      }
    }
  }
  __syncthreads();                                 // LDS reuse across items
}

__global__ __launch_bounds__(256) void kc_score(
    const float* __restrict__ f0, const float* __restrict__ f1,
    const float* __restrict__ f2,
    const float* __restrict__ b0, const float* __restrict__ b1,
    const float* __restrict__ b2, float* __restrict__ ws) {
  __shared__ float partial[1024];
  __shared__ float sig[85];
  int tid = threadIdx.x;
  int reg = blockIdx.x >> 3, ci0 = blockIdx.x & 7;  // grid = 700*8
  int cnt = min(((int*)ws)[CNTB_F + reg], NSLOT);
  for (int ci = ci0; ci < cnt; ci += 8) {           // ~1 candidate per block
    int* cd = (int*)ws + CANDB_F + (reg * NSLOT + ci) * 2;
    int code = cd[0]; float obj = ((float*)cd)[1];
    int n = code >> 24, level = (code >> 20) & 15, a = (code >> 16) & 3, s = code & 0xFFFF;
    if (level == 0)
      kc_block<128, 6400, 80>(0, n, a, s, obj, f0, ws + WT_F + WT_L0, b0, ws, partial, sig, tid);
    else if (level == 1)
      kc_block<256, 1600, 40>(1, n, a, s, obj, f1, ws + WT_F + WT_L1, b1, ws, partial, sig, tid);
    else
      kc_block<512, 400, 20>(2, n, a, s, obj, f2, ws + WT_F + WT_L2, b2, ws, partial, sig, tid);
  }
}

// ------------------------------------------ KD: per-image greedy NMS -------
// Writes its ENTIRE 600-float output slice (zero rows on early exit), so
// d_out needs no pre-zeroing kernel.
__global__ __launch_bounds__(256) void kd_nms(
    const float* __restrict__ ws, float* __restrict__ out,
    const float* __restrict__ sfp) {
  __shared__ float bx1[CAP2], by1[CAP2], bx2[CAP2], by2[CAP2], bsc[CAP2], blb[CAP2];
  __shared__ int bval[CAP2];
  __shared__ float rs[256];
  __shared__ int ri[256];
  int n = blockIdx.x, tid = threadIdx.x;
  int cnt = min(((const int*)ws)[IMGCNT_F + n], CAP2);
  for (int i = tid; i < cnt; i += 256) {
    const float* src = ws + IMGBUF_F + ((size_t)(n * CAP2 + i)) * 6;
    bx1[i] = src[0]; by1[i] = src[1]; bx2[i] = src[2]; by2[i] = src[3];
    bsc[i] = src[4]; blb[i] = src[5]; bval[i] = 1;
  }
  __syncthreads();
  float sf = sfp[n];
  for (int it = 0; it < 100; ++it) {
    float best = -1.f; int bi = -1;
    for (int i = tid; i < cnt; i += 256)
      if (bval[i] && bsc[i] > best) { best = bsc[i]; bi = i; }
    rs[tid] = best; ri[tid] = bi;
    __syncthreads();
    for (int off = 128; off > 0; off >>= 1) {
      if (tid < off && rs[tid + off] > rs[tid]) { rs[tid] = rs[tid + off]; ri[tid] = ri[tid + off]; }
      __syncthreads();
    }
    int wi = ri[0]; float wsc = rs[0];
    if (wi < 0) {                         // no valid left: zero-fill remaining
      for (int r2 = it * 6 + tid; r2 < 600; r2 += 256)
        out[(size_t)n * 600 + r2] = 0.f;
      break;
    }
    if (tid == 0) {
      float* o = out + (size_t)(n * 100 + it) * 6;
      o[0] = bx1[wi] / sf; o[1] = by1[wi] / sf;
      o[2] = bx2[wi] / sf; o[3] = by2[wi] / sf;
      o[4] = wsc;          o[5] = blb[wi];
    }
    // suppress IoU > 0.6 on class-offset boxes (offset adds to all 4 coords)
    float ofw = blb[wi] * IMG_F;
    float wx1 = bx1[wi] + ofw, wy1 = by1[wi] + ofw;
    float wx2 = bx2[wi] + ofw, wy2 = by2[wi] + ofw;
    float wa = (wx2 - wx1) * (wy2 - wy1);
    for (int i = tid; i < cnt; i += 256) {
      if (bval[i]) {
        float o2 = blb[i] * IMG_F;
        float x1 = bx1[i] + o2, y1 = by1[i] + o2, x2 = bx2[i] + o2, y2 = by2[i] + o2;
        float iw = fmaxf(fminf(wx2, x2) - fmaxf(wx1, x1), 0.f);
        float ih = fmaxf(fminf(wy2, y2) - fmaxf(wy1, y1), 0.f);
        float inter = iw * ih;
        float area = (x2 - x1) * (y2 - y1);
        float iou = inter / (wa + area - inter + 1e-7f);
        if (iou > 0.6f) bval[i] = 0;
      }
    }
    if (tid == 0) bval[wi] = 0;
    __syncthreads();
  }
}

// ---------------------------------------------------------------------------
extern "C" void kernel_launch(void* const* d_in, const int* in_sizes, int n_in,
                              void* d_out, int out_size, void* d_ws, size_t ws_size,
                              hipStream_t stream) {
  // setup_inputs() dict order: f0,w0,b0, f1,w1,b1, f2,w2,b2, scale_factors
  const float* f0 = (const float*)d_in[0];
  const float* w0 = (const float*)d_in[1];
  const float* b0 = (const float*)d_in[2];
  const float* f1 = (const float*)d_in[3];
  const float* w1 = (const float*)d_in[4];
  const float* b1 = (const float*)d_in[5];
  const float* f2 = (const float*)d_in[6];
  const float* w2 = (const float*)d_in[7];
  const float* b2 = (const float*)d_in[8];
  const float* sf = (const float*)d_in[9];
  float* out = (float*)d_out;
  float* ws  = (float*)d_ws;    // needs ~2.1 MB

  kb_obj  <<<700,     256, 0, stream>>>(f0, f1, f2, w0, w1, w2, b0, b1, b2, ws);
  kc_score<<<700 * 8, 256, 0, stream>>>(f0, f1, f2, b0, b1, b2, ws);
  kd_nms  <<<8,       256, 0, stream>>>(ws, out, sf);
}